// Round 4
// baseline (410.556 us; speedup 1.0000x reference)
//
#include <hip/hip_runtime.h>

#define DD 512
#define DKk 100
#define NT 7            // ceil(100/16) column tiles
#define CHUNK 16
#define LDS_STRIDE 520  // shorts per staged row (+8 pad: 2-way banks, free)

typedef __attribute__((ext_vector_type(8))) short short8;
typedef __attribute__((ext_vector_type(4))) short short4v;
typedef __attribute__((ext_vector_type(4))) float f32x4;

struct AttendArgs {
  const float* feats[4];
  const float* wfeat[4];
  const float* wf[4];
  const float* bias[4];
  int   N[4];
  float coef[4];
};

// fp32 -> bf16 bits, round-to-nearest-even
__device__ __forceinline__ short f2bf(float x) {
  unsigned u = __builtin_bit_cast(unsigned, x);
  unsigned r = (u + 0x7fffu + ((u >> 16) & 1u)) >> 16;
  return (short)r;
}

__device__ __forceinline__ float bf2f(unsigned short b) {
  unsigned u = ((unsigned)b) << 16;
  return __builtin_bit_cast(float, u);
}

__device__ __forceinline__ float fast_tanh(float x) {
  const float e = __expf(2.0f * x);
  return 1.0f - 2.0f / (e + 1.0f);
}

// ---------------------------------------------------------------------------
// Setup: w_feat (512x100 fp32) -> MFMA B-fragment-ordered bf16 (as R3).
// ---------------------------------------------------------------------------
__global__ void wprep_kernel(AttendArgs args, unsigned short* __restrict__ wfrag) {
  const int a = blockIdx.x / NT;
  const int t = blockIdx.x % NT;
  const int tid = threadIdx.x;
  const int lane = tid & 63;
  const int m = lane & 15;
  const int q = lane >> 4;
  const int kg = tid >> 6;
  const int col = t * 16 + m;
  const float* __restrict__ w = args.wfeat[a];
  unsigned short* __restrict__ dst = wfrag + (size_t)((a * NT + t) * 16) * 512;
  #pragma unroll
  for (int i = 0; i < 4; ++i) {
    const int ks = kg * 4 + i;
    short8 v;
    #pragma unroll
    for (int j = 0; j < 8; ++j) {
      const int d = ks * 32 + q * 8 + j;
      v[j] = (col < DKk) ? f2bf(w[d * DKk + col]) : (short)0;
    }
    *reinterpret_cast<short8*>(dst + (size_t)ks * 512 + lane * 8) = v;
  }
}

// ---------------------------------------------------------------------------
// Single-pass flash-style fused kernel, one block per (a,b), 512 thr = 8 waves.
// Per 16-row chunk: stage fp32->bf16 LDS -> MFMA scores -> tanh*wf reduce ->
// online softmax (m,l) + O[d] += e_i * feats_bf16[i][d] from LDS. No reread.
// mfma 16x16x32_bf16: A[m=lane&15][k=(lane>>4)*8+j], D: col=lane&15,
// row=(lane>>4)*4+reg (HW-verified R1/R3).
// ---------------------------------------------------------------------------
__global__ __launch_bounds__(512, 4)
void fused_kernel(AttendArgs args, const unsigned short* __restrict__ wfrag,
                  float* __restrict__ out) {
  const int a = blockIdx.x & 3;
  const int b = blockIdx.x >> 2;
  const int tid = threadIdx.x;
  const int lane = tid & 63;
  const int wave = tid >> 6;          // col tile (0..6); wave 7 helps stage/flash
  const int m = lane & 15;
  const int q = lane >> 4;
  const int N = args.N[a];
  const float* __restrict__ feats = args.feats[a] + (size_t)b * (size_t)N * DD;
  const float* __restrict__ wfp = args.wf[a];
  const float* __restrict__ bias = args.bias[a];

  __shared__ __align__(16) unsigned short f_lds[2][CHUNK][LDS_STRIDE];
  __shared__ float score_lds[2][CHUNK];   // double-buffered per-chunk scores

  // --- B fragments (pre-formatted, coalesced, L2-hot) ---
  short8 bfrag[16];
  float wfv = 0.f;
  if (wave < NT) {
    const int col = wave * 16 + m;
    wfv = (col < DKk) ? wfp[col] : 0.f;
    const unsigned short* src = wfrag + (size_t)((a * NT + wave) * 16) * 512 + lane * 8;
    #pragma unroll
    for (int ks = 0; ks < 16; ++ks)
      bfrag[ks] = *reinterpret_cast<const short8*>(src + (size_t)ks * 512);
  }

  const int nchunks = (N + CHUNK - 1) / CHUNK;

  // flash state: per-thread O for dim d=tid; m/l replicated (identical all thr)
  float O = 0.f, m_run = -1e30f, l_run = 0.f;

  // --- prefetch chunk 0 (4 float4/thread = 16 rows x 512 fp32) ---
  float4 pf[4];
  #pragma unroll
  for (int it = 0; it < 4; ++it) {
    const int idx = tid + it * 512;
    const int row = idx >> 7;
    const int c4 = idx & 127;
    pf[it] = (row < N)
      ? *reinterpret_cast<const float4*>(feats + (size_t)row * DD + (c4 << 2))
      : make_float4(0.f, 0.f, 0.f, 0.f);
  }

  for (int c = 0; c < nchunks; ++c) {
    const int bufc = c & 1;
    const int n0 = c * CHUNK;
    // stage regs -> bf16 LDS
    #pragma unroll
    for (int it = 0; it < 4; ++it) {
      const int idx = tid + it * 512;
      const int row = idx >> 7;
      const int c4 = idx & 127;
      short4v pk = { f2bf(pf[it].x), f2bf(pf[it].y), f2bf(pf[it].z), f2bf(pf[it].w) };
      *reinterpret_cast<short4v*>(&f_lds[bufc][row][c4 << 2]) = pk;
    }
    // init score slab: bias for valid rows, -inf for pad rows
    if (tid < CHUNK)
      score_lds[bufc][tid] = (n0 + tid < N) ? bias[n0 + tid] : -1e30f;
    __syncthreads();  // B1: staging visible; prior flash-update done block-wide

    // issue prefetch AFTER the barrier -> hides behind MFMA+epilogue,
    // drains at B2 instead of serializing at B1 (R3's mistake).
    if (c + 1 < nchunks) {
      const int n0n = n0 + CHUNK;
      #pragma unroll
      for (int it = 0; it < 4; ++it) {
        const int idx = tid + it * 512;
        const int row = n0n + (idx >> 7);
        const int c4 = idx & 127;
        pf[it] = (row < N)
          ? *reinterpret_cast<const float4*>(feats + (size_t)row * DD + (c4 << 2))
          : make_float4(0.f, 0.f, 0.f, 0.f);
      }
    }

    if (wave < NT) {
      f32x4 acc = {0.f, 0.f, 0.f, 0.f};
      #pragma unroll
      for (int ks = 0; ks < 16; ++ks) {
        const short8 af = *reinterpret_cast<const short8*>(&f_lds[bufc][m][ks * 32 + q * 8]);
        acc = __builtin_amdgcn_mfma_f32_16x16x32_bf16(af, bfrag[ks], acc, 0, 0, 0);
      }
      float part[4];
      #pragma unroll
      for (int r = 0; r < 4; ++r) part[r] = fast_tanh(acc[r]) * wfv;
      #pragma unroll
      for (int mask = 1; mask <= 8; mask <<= 1) {
        #pragma unroll
        for (int r = 0; r < 4; ++r) part[r] += __shfl_xor(part[r], mask, 64);
      }
      if (m == 0) {
        #pragma unroll
        for (int r = 0; r < 4; ++r)
          atomicAdd(&score_lds[bufc][q * 4 + r], part[r]);
      }
    }
    __syncthreads();  // B2: chunk scores complete (pf drains here, post-MFMA)

    // --- online softmax + O accumulation from LDS bf16 copy ---
    float m_new = m_run;
    #pragma unroll
    for (int i = 0; i < CHUNK; ++i) m_new = fmaxf(m_new, score_lds[bufc][i]);
    const float alpha = __expf(m_run - m_new);
    float o = O * alpha;
    float esum0 = 0.f, esum1 = 0.f;
    float o1 = 0.f;
    #pragma unroll
    for (int i = 0; i < CHUNK; i += 2) {
      const float e0 = __expf(score_lds[bufc][i] - m_new);
      const float e1 = __expf(score_lds[bufc][i + 1] - m_new);
      esum0 += e0; esum1 += e1;
      o  += e0 * bf2f(f_lds[bufc][i][tid]);
      o1 += e1 * bf2f(f_lds[bufc][i + 1][tid]);
    }
    O = o + o1;
    l_run = l_run * alpha + esum0 + esum1;
    m_run = m_new;
    // no trailing barrier: next iter uses the other buffers; B1 orders reuse
  }

  atomicAdd(&out[(size_t)b * DD + tid], args.coef[a] * O / l_run);
}

extern "C" void kernel_launch(void* const* d_in, const int* in_sizes, int n_in,
                              void* d_out, int out_size, void* d_ws, size_t ws_size,
                              hipStream_t stream) {
  AttendArgs args;
  args.feats[0] = (const float*)d_in[0];
  args.wfeat[0] = (const float*)d_in[4];
  args.wf[0]    = (const float*)d_in[6];          // vec_first=False: wf = w_p[:100]
  args.bias[0]  = (const float*)d_in[7];
  args.N[0] = 196; args.coef[0] = 1.0f;

  args.feats[1] = (const float*)d_in[1];
  args.wfeat[1] = (const float*)d_in[9];
  args.wf[1]    = (const float*)d_in[10] + 100;   // vec_first=True: wf = w_p[100:]
  args.bias[1]  = (const float*)d_in[11];
  args.N[1] = 200; args.coef[1] = 1.0f;

  args.feats[2] = (const float*)d_in[2];
  args.wfeat[2] = (const float*)d_in[13];
  args.wf[2]    = (const float*)d_in[14] + 100;
  args.bias[2]  = (const float*)d_in[15];
  args.N[2] = 200; args.coef[2] = 0.5f;

  args.feats[3] = (const float*)d_in[3];
  args.wfeat[3] = (const float*)d_in[17];
  args.wf[3]    = (const float*)d_in[18] + 100;
  args.bias[3]  = (const float*)d_in[19];
  args.N[3] = 50;  args.coef[3] = 0.5f;

  unsigned short* wfrag = (unsigned short*)d_ws;  // 4*7*16*512*2 = 458,752 B

  hipMemsetAsync(d_out, 0, (size_t)out_size * sizeof(float), stream);
  wprep_kernel<<<dim3(4 * NT), dim3(256), 0, stream>>>(args, wfrag);
  fused_kernel<<<dim3(4 * 256), dim3(512), 0, stream>>>(args, wfrag, (float*)d_out);
}